// Round 19
// baseline (87.132 us; speedup 1.0000x reference)
//
#include <hip/hip_runtime.h>

// Event-to-image: B=16, N=500000 events (t,x,y,p) f32 -> (16,720,1280,3) f32.
// Last-event-wins per pixel: p==1 -> (0,255,255); p==0 -> (255,0,255);
// untouched -> (255,255,510). Order-independent via max over
// key = ((event_idx+1)<<1)|p (20 bits), pk = pos<<20 | key,
// pos = (y - 3*band)*1280 + x (<3840, 12 bits) -- 3-row bands (240/batch).
//
// R19: render split into winner_k (gather -> byte state image, latency part)
// + paint_k (pure grid-stride streaming write, fill-shaped: no LDS, no
// barriers). R14-R18 falsified preamble/search/store-flavor as render's
// slack; remaining suspect is the fused gather|barrier|store phase convoy
// keeping the 177MB stream at 4.2 TB/s while a pure-write kernel (harness
// fill) sustains 7 TB/s on this chip. Costs +30MB state round-trip.

#define WIDTH   1280
#define HEIGHT  720
#define BATCH   16
#define NEV     500000
#define THREADS 512                         // scatter block
#define EPT     16
#define EVPB    (THREADS * EPT)             // 8192 events per block
#define BPB     ((NEV + EVPB - 1) / EVPB)   // 62 blocks per batch
#define NBLK    (BATCH * BPB)               // 992
#define NBANDS  240                         // 3-row bands per batch
#define PH      (NBANDS + 1)                // 241 prefix rows
#define RTHREADS 256
#define BPX     (3 * WIDTH)                 // 3840 pixels per band
#define NPIX    (BATCH * HEIGHT * WIDTH)    // 14,745,600
#define T4      (NPIX * 3 / 4)              // 11,059,200 output float4s
#define PAINTBLK 2048

typedef float f4 __attribute__((ext_vector_type(4)));

// ws layout: [0, 956KB)=pref_g (band-major); [0x400000, +32.5MB)=bins;
//            [0x2400000, +14.07MB)=state bytes. Total ~51.8MB (ws >= 59MB, R1).

__global__ __launch_bounds__(THREADS, 8) void scatter_k(const float4* __restrict__ ev,
                                                        unsigned int* __restrict__ pref_g,
                                                        unsigned int* __restrict__ bins) {
    __shared__ unsigned int hist[NBANDS];
    __shared__ unsigned int offs[NBANDS];
    __shared__ unsigned int stage[EVPB];     // 32 KB (total ~34 KB -> 4 blocks/CU)

    int t = threadIdx.x;
    int batch = blockIdx.x / BPB;
    int blk   = blockIdx.x % BPB;
    int ev0   = blk * EVPB;
    int cnt   = NEV - ev0; if (cnt > EVPB) cnt = EVPB;
    const f4* bevv = (const f4*)(ev + (size_t)batch * NEV + ev0);

    if (t < NBANDS) hist[t] = 0u;
    __syncthreads();

    // pass 1: ONE global read (nt, batched x4 for MLP), pack to registers
    unsigned int pkd[EPT];   // bd<<22 | y<<12 | x<<1 | p ; 0xFFFFFFFF = tail
    if (cnt == EVPB) {
#pragma unroll
        for (int h = 0; h < EPT / 4; ++h) {
            f4 vv[4];
#pragma unroll
            for (int k = 0; k < 4; ++k)
                vv[k] = __builtin_nontemporal_load(&bevv[t + (h * 4 + k) * THREADS]);
#pragma unroll
            for (int k = 0; k < 4; ++k) {
                unsigned int yi = (unsigned int)(int)vv[k].z;
                unsigned int xi = (unsigned int)(int)vv[k].y;
                unsigned int pb = (vv[k].w == 1.0f) ? 1u : 0u;
                unsigned int bd = yi / 3u;
                pkd[h * 4 + k] = (bd << 22) | (yi << 12) | (xi << 1) | pb;
                atomicAdd(&hist[bd], 1u);
            }
        }
    } else {
#pragma unroll
        for (int k = 0; k < EPT; ++k) {
            int e = t + k * THREADS;
            unsigned int c = 0xFFFFFFFFu;
            if (e < cnt) {
                f4 v = __builtin_nontemporal_load(&bevv[e]);
                unsigned int yi = (unsigned int)(int)v.z;
                unsigned int xi = (unsigned int)(int)v.y;
                unsigned int pb = (v.w == 1.0f) ? 1u : 0u;
                unsigned int bd = yi / 3u;
                c = (bd << 22) | (yi << 12) | (xi << 1) | pb;
                atomicAdd(&hist[bd], 1u);
            }
            pkd[k] = c;
        }
    }
    __syncthreads();

    // exclusive prefix over 240 bands: wave 0 only, threads 0..59 own 4 bands
    if (t < 60) {
        int b4 = t * 4;
        unsigned int own = hist[b4] + hist[b4 + 1] + hist[b4 + 2] + hist[b4 + 3];
        unsigned int incl = own;
        for (int d = 1; d < 64; d <<= 1) {
            unsigned int n = __shfl_up(incl, d);
            if (t >= d) incl += n;
        }
        unsigned int run = incl - own;
        offs[b4] = run;          run += hist[b4];
        offs[b4 + 1] = run;      run += hist[b4 + 1];
        offs[b4 + 2] = run;      run += hist[b4 + 2];
        offs[b4 + 3] = run;
    }
    __syncthreads();

    // publish band-major prefix BEFORE pass 2 mutates offs
    {
        unsigned int* pp = pref_g + (size_t)batch * BPB + blk;
        for (int r = t; r < PH; r += THREADS)
            pp[(size_t)r * (BATCH * BPB)] = (r < NBANDS) ? offs[r] : (unsigned int)cnt;
    }
    __syncthreads();

    // pass 2: from REGISTERS, rank, place band-sorted into stage
    if (cnt == EVPB) {
#pragma unroll
        for (int k = 0; k < EPT; ++k) {
            unsigned int c   = pkd[k];
            unsigned int bd  = c >> 22;
            unsigned int yi  = (c >> 12) & 0x3FFu;
            unsigned int xi  = (c >> 1) & 0x7FFu;
            unsigned int pos = (yi - bd * 3u) * 1280u + xi;
            unsigned int e   = (unsigned int)(t + k * THREADS);
            unsigned int pk  = (pos << 20)
                             | (((unsigned int)ev0 + e + 1u) << 1) | (c & 1u);
            unsigned int slot = atomicAdd(&offs[bd], 1u);
            stage[slot] = pk;
        }
    } else {
#pragma unroll
        for (int k = 0; k < EPT; ++k) {
            unsigned int c = pkd[k];
            if (c != 0xFFFFFFFFu) {
                unsigned int bd  = c >> 22;
                unsigned int yi  = (c >> 12) & 0x3FFu;
                unsigned int xi  = (c >> 1) & 0x7FFu;
                unsigned int pos = (yi - bd * 3u) * 1280u + xi;
                unsigned int e   = (unsigned int)(t + k * THREADS);
                unsigned int pk  = (pos << 20)
                                 | (((unsigned int)ev0 + e + 1u) << 1) | (c & 1u);
                unsigned int slot = atomicAdd(&offs[bd], 1u);
                stage[slot] = pk;
            }
        }
    }
    __syncthreads();

    // write the sorted chunk, fully coalesced
    uint4* dst = (uint4*)(bins + (size_t)blockIdx.x * EVPB);
    const uint4* src = (const uint4*)stage;
    for (int k = t; k < EVPB / 4; k += THREADS)
        dst[k] = src[k];
}

__global__ __launch_bounds__(RTHREADS) void winner_k(const unsigned int* __restrict__ pref_g,
                                                     const unsigned int* __restrict__ bins,
                                                     unsigned int* __restrict__ state4) {
    __shared__ unsigned int win[BPX];        // 3840 px, 15 KB
    __shared__ unsigned int segbase[BPB];
    __shared__ unsigned int segpref[65];

    int t = threadIdx.x;
    int bandid = blockIdx.x;                 // batch*240 + band
    int batch = bandid / NBANDS;
    int band  = bandid - batch * NBANDS;

    // issue the two coalesced pref rows first; zero win while they fly
    unsigned int p0 = 0u, p1 = 0u;
    if (t < BPB) {
        const unsigned int* r0 = pref_g + ((size_t)band * BATCH + batch) * BPB;
        const unsigned int* r1 = pref_g + ((size_t)(band + 1) * BATCH + batch) * BPB;
        p0 = r0[t];
        p1 = r1[t];
    }
    for (int x = t; x < BPX; x += RTHREADS) win[x] = 0u;

    unsigned int mycnt = 0u;
    if (t < BPB) {
        segbase[t] = (unsigned int)((batch * BPB + t) * EVPB) + p0;
        mycnt = p1 - p0;
    }
    if (t < 64) {                            // wave-0 inclusive scan of 62 counts
        unsigned int v = mycnt;
        for (int d = 1; d < 64; d <<= 1) {
            unsigned int n = __shfl_up(v, d);
            if (t >= d) v += n;
        }
        if (t == 0) segpref[0] = 0u;
        segpref[t + 1] = v;
    }
    __syncthreads();

    unsigned int total = segpref[BPB];       // ~2083
    for (unsigned int j = t; j < total; j += RTHREADS) {
        int lo = 0, hi = BPB - 1;            // largest s with segpref[s] <= j
        while (lo < hi) {
            int mid = (lo + hi + 1) >> 1;
            if (segpref[mid] <= j) lo = mid; else hi = mid - 1;
        }
        unsigned int pk = bins[segbase[lo] + (j - segpref[lo])];
        atomicMax(&win[pk >> 20], pk & 0xFFFFFu);   // LDS atomic
    }
    __syncthreads();

    // pack 4 pixel states/thread: 0=untouched, 1=p0-wins, 2=p1-wins
    const uint4* w4 = (const uint4*)win;
    for (int g = t; g < BPX / 4; g += RTHREADS) {
        uint4 ww = w4[g];
        unsigned int s0 = ww.x ? 1u + (ww.x & 1u) : 0u;
        unsigned int s1 = ww.y ? 1u + (ww.y & 1u) : 0u;
        unsigned int s2 = ww.z ? 1u + (ww.z & 1u) : 0u;
        unsigned int s3 = ww.w ? 1u + (ww.w & 1u) : 0u;
        state4[(size_t)bandid * (BPX / 4) + g] = s0 | (s1 << 8) | (s2 << 16) | (s3 << 24);
    }
}

__global__ __launch_bounds__(RTHREADS) void paint_k(const unsigned char* __restrict__ state,
                                                    float4* __restrict__ out) {
    // pure streaming: one float4 per thread per iteration, grid-stride,
    // no LDS, no barriers. Each float4 spans at most 2 pixels.
    for (unsigned int j = blockIdx.x * RTHREADS + threadIdx.x; j < T4;
         j += PAINTBLK * RTHREADS) {
        unsigned int fi0 = j * 4u;
        unsigned int px0 = fi0 / 3u;          // magic-mul
        unsigned int r   = fi0 - px0 * 3u;
        unsigned int s0 = state[px0];
        unsigned int s1 = state[px0 + 1u > (unsigned int)(NPIX - 1) ? (unsigned int)(NPIX - 1) : px0 + 1u];
        float vals[4];
#pragma unroll
        for (unsigned int c = 0; c < 4; ++c) {
            unsigned int rc = r + c;
            unsigned int s  = (rc < 3u) ? s0 : s1;
            unsigned int ch = (rc < 3u) ? rc : rc - 3u;
            float v;
            if (ch == 0u)      v = (s == 2u) ? 0.0f : 255.0f;
            else if (ch == 1u) v = (s == 1u) ? 0.0f : 255.0f;
            else               v = (s == 0u) ? 510.0f : 255.0f;
            vals[c] = v;
        }
        out[j] = make_float4(vals[0], vals[1], vals[2], vals[3]);
    }
}

extern "C" void kernel_launch(void* const* d_in, const int* in_sizes, int n_in,
                              void* d_out, int out_size, void* d_ws, size_t ws_size,
                              hipStream_t stream) {
    const float4* ev = (const float4*)d_in[0];
    unsigned int* pref_g = (unsigned int*)d_ws;
    unsigned int* bins   = (unsigned int*)((char*)d_ws + 0x400000);
    unsigned char* state = (unsigned char*)d_ws + 0x2400000;
    float4* out = (float4*)d_out;

    scatter_k<<<NBLK, THREADS, 0, stream>>>(ev, pref_g, bins);
    winner_k<<<BATCH * NBANDS, RTHREADS, 0, stream>>>(pref_g, bins, (unsigned int*)state);
    paint_k<<<PAINTBLK, RTHREADS, 0, stream>>>(state, out);
}

// Round 20
// 86.352 us; speedup vs baseline: 1.0090x; 1.0090x over previous
//
#include <hip/hip_runtime.h>

// Event-to-image: B=16, N=500000 events (t,x,y,p) f32 -> (16,720,1280,3) f32.
// Last-event-wins per pixel: p==1 -> (0,255,255); p==0 -> (255,0,255);
// untouched -> (255,255,510). Order-independent via max over
// key = ((event_idx+1)<<1)|p (20 bits), pk = pos<<20 | key,
// pos = (y - 3*band)*1280 + x (<3840, 12 bits) -- 3-row bands (240/batch).
//
// R20: R19 proved the GATHER phase is render's ~20us slack (winner_k >= 23us
// for 50MB); R16 proved contiguous band deposits make render lean (~33us)
// but lost 26us in scatter (3 blocks/CU via +8KB bandidx). Fix: band-MAJOR
// copy-out needs no bandidx -- after pass 2, offs[bd-1]/offs[bd] are band
// bd's start/end in stage; wave w copies bands [30w,30w+30) to their
// reserved contiguous runs (adj[bd]+rank). LDS 35KB -> 4 blocks x 8 waves
// = 32 waves/CU kept. Render = one dense coalesced read + LDS atomicMax +
// interleaved plain float4 stores.

#define WIDTH   1280
#define HEIGHT  720
#define BATCH   16
#define NEV     500000
#define THREADS 512                         // scatter block
#define EPT     16
#define EVPB    (THREADS * EPT)             // 8192 events per block
#define BPB     ((NEV + EVPB - 1) / EVPB)   // 62 blocks per batch
#define NBLK    (BATCH * BPB)               // 992
#define NBANDS  240                         // 3-row bands per batch
#define NBTOT   (BATCH * NBANDS)            // 3840 band regions
#define BANDCAP 3072                        // lambda~2083 + 21 sigma
#define RTHREADS 256
#define BPX     (3 * WIDTH)                 // 3840 pixels per band
#define BANDS_PER_WAVE (NBANDS / 8)         // 30 (512 threads = 8 waves)

typedef float f4 __attribute__((ext_vector_type(4)));

// ws layout: [0, NBTOT*4)=gcount (15KB); [0x10000, +NBTOT*BANDCAP*4)=bins (47.2MB)

__global__ __launch_bounds__(THREADS, 8) void scatter_k(const float4* __restrict__ ev,
                                                        unsigned int* __restrict__ gcount,
                                                        unsigned int* __restrict__ bins) {
    __shared__ unsigned int hist[NBANDS];
    __shared__ unsigned int offs[NBANDS];
    __shared__ unsigned int adj[NBANDS];
    __shared__ unsigned int stage[EVPB];     // 32 KB; total ~35 KB -> 4 blocks/CU

    int t = threadIdx.x;
    int batch = blockIdx.x / BPB;
    int blk   = blockIdx.x % BPB;
    int ev0   = blk * EVPB;
    int cnt   = NEV - ev0; if (cnt > EVPB) cnt = EVPB;
    const f4* bevv = (const f4*)(ev + (size_t)batch * NEV + ev0);

    if (t < NBANDS) hist[t] = 0u;
    __syncthreads();

    // pass 1: ONE global read (nt, batched x4 for MLP), pack to registers
    unsigned int pkd[EPT];   // bd<<22 | y<<12 | x<<1 | p ; 0xFFFFFFFF = tail
    if (cnt == EVPB) {
#pragma unroll
        for (int h = 0; h < EPT / 4; ++h) {
            f4 vv[4];
#pragma unroll
            for (int k = 0; k < 4; ++k)
                vv[k] = __builtin_nontemporal_load(&bevv[t + (h * 4 + k) * THREADS]);
#pragma unroll
            for (int k = 0; k < 4; ++k) {
                unsigned int yi = (unsigned int)(int)vv[k].z;
                unsigned int xi = (unsigned int)(int)vv[k].y;
                unsigned int pb = (vv[k].w == 1.0f) ? 1u : 0u;
                unsigned int bd = yi / 3u;
                pkd[h * 4 + k] = (bd << 22) | (yi << 12) | (xi << 1) | pb;
                atomicAdd(&hist[bd], 1u);
            }
        }
    } else {
#pragma unroll
        for (int k = 0; k < EPT; ++k) {
            int e = t + k * THREADS;
            unsigned int c = 0xFFFFFFFFu;
            if (e < cnt) {
                f4 v = __builtin_nontemporal_load(&bevv[e]);
                unsigned int yi = (unsigned int)(int)v.z;
                unsigned int xi = (unsigned int)(int)v.y;
                unsigned int pb = (v.w == 1.0f) ? 1u : 0u;
                unsigned int bd = yi / 3u;
                c = (bd << 22) | (yi << 12) | (xi << 1) | pb;
                atomicAdd(&hist[bd], 1u);
            }
            pkd[k] = c;
        }
    }
    __syncthreads();

    // exclusive prefix over 240 bands: wave 0 only, threads 0..59 own 4 bands
    if (t < 60) {
        int b4 = t * 4;
        unsigned int own = hist[b4] + hist[b4 + 1] + hist[b4 + 2] + hist[b4 + 3];
        unsigned int incl = own;
        for (int d = 1; d < 64; d <<= 1) {
            unsigned int n = __shfl_up(incl, d);
            if (t >= d) incl += n;
        }
        unsigned int run = incl - own;
        offs[b4] = run;          run += hist[b4];
        offs[b4 + 1] = run;      run += hist[b4 + 1];
        offs[b4 + 2] = run;      run += hist[b4 + 2];
        offs[b4 + 3] = run;
    }
    __syncthreads();

    // reserve contiguous global runs (one far atomic per band, fire early)
    if (t < NBANDS) {
        unsigned int h = hist[t];
        unsigned int rb = h ? atomicAdd(&gcount[batch * NBANDS + t], h) : 0u;
        adj[t] = (unsigned int)(batch * NBANDS + t) * BANDCAP + rb;
    }

    // pass 2: from REGISTERS, rank, place band-sorted into stage
    // (no barrier needed before: pass 2 touches offs/stage, reservation adj)
    if (cnt == EVPB) {
#pragma unroll
        for (int k = 0; k < EPT; ++k) {
            unsigned int c   = pkd[k];
            unsigned int bd  = c >> 22;
            unsigned int yi  = (c >> 12) & 0x3FFu;
            unsigned int xi  = (c >> 1) & 0x7FFu;
            unsigned int pos = (yi - bd * 3u) * 1280u + xi;
            unsigned int e   = (unsigned int)(t + k * THREADS);
            unsigned int pk  = (pos << 20)
                             | (((unsigned int)ev0 + e + 1u) << 1) | (c & 1u);
            unsigned int slot = atomicAdd(&offs[bd], 1u);
            stage[slot] = pk;
        }
    } else {
#pragma unroll
        for (int k = 0; k < EPT; ++k) {
            unsigned int c = pkd[k];
            if (c != 0xFFFFFFFFu) {
                unsigned int bd  = c >> 22;
                unsigned int yi  = (c >> 12) & 0x3FFu;
                unsigned int xi  = (c >> 1) & 0x7FFu;
                unsigned int pos = (yi - bd * 3u) * 1280u + xi;
                unsigned int e   = (unsigned int)(t + k * THREADS);
                unsigned int pk  = (pos << 20)
                                 | (((unsigned int)ev0 + e + 1u) << 1) | (c & 1u);
                unsigned int slot = atomicAdd(&offs[bd], 1u);
                stage[slot] = pk;
            }
        }
    }
    __syncthreads();

    // band-major copy-out: wave w owns bands [30w, 30w+30). After pass 2,
    // offs[bd] = band end; start = bd ? offs[bd-1] : 0. dest = adj[bd]+rank.
    {
        int w = t >> 6, l = t & 63;
        int bd0 = w * BANDS_PER_WAVE;
        for (int bd = bd0; bd < bd0 + BANDS_PER_WAVE; ++bd) {
            unsigned int start = bd ? offs[bd - 1] : 0u;
            unsigned int end   = offs[bd];
            unsigned int dst   = adj[bd];
            for (unsigned int e = start + (unsigned int)l; e < end; e += 64u)
                bins[dst + (e - start)] = stage[e];
        }
    }
}

__global__ __launch_bounds__(RTHREADS) void render_k(const unsigned int* __restrict__ gcount,
                                                     const unsigned int* __restrict__ bins,
                                                     float4* __restrict__ out) {
    __shared__ unsigned int win[BPX];        // 3840 px, 15 KB

    int t = threadIdx.x;
    int bandid = blockIdx.x;                 // batch*240 + band

    unsigned int cnt = gcount[bandid];
    if (cnt > BANDCAP) cnt = BANDCAP;

    for (int x = t; x < BPX; x += RTHREADS) win[x] = 0u;
    __syncthreads();

    // gather: ONE dense contiguous coalesced run
    const unsigned int* bb = bins + (size_t)bandid * BANDCAP;
    for (unsigned int j = t; j < cnt; j += RTHREADS) {
        unsigned int pk = bb[j];
        atomicMax(&win[pk >> 20], pk & 0xFFFFFu);   // LDS atomic
    }
    __syncthreads();

    // write three image rows: 2880 float4, one per thread per iteration
    // (lane-contiguous 1024B per store instruction), plain stores
    float4* orow = (float4*)out + (size_t)bandid * (BPX * 3 / 4);
    for (int j = t; j < BPX * 3 / 4; j += RTHREADS) {
        float vals[4];
#pragma unroll
        for (int c = 0; c < 4; ++c) {
            int fi = j * 4 + c;
            int px = fi / 3;
            int ch = fi - px * 3;
            unsigned int k = win[px];
            float val;
            if (k == 0u) val = (ch == 2) ? 510.0f : 255.0f;
            else if (ch == 2) val = 255.0f;
            else if (ch == 0) val = (k & 1u) ? 0.0f : 255.0f;
            else              val = (k & 1u) ? 255.0f : 0.0f;
            vals[c] = val;
        }
        orow[j] = make_float4(vals[0], vals[1], vals[2], vals[3]);
    }
}

extern "C" void kernel_launch(void* const* d_in, const int* in_sizes, int n_in,
                              void* d_out, int out_size, void* d_ws, size_t ws_size,
                              hipStream_t stream) {
    const float4* ev = (const float4*)d_in[0];
    unsigned int* gcount = (unsigned int*)d_ws;
    unsigned int* bins   = (unsigned int*)((char*)d_ws + 0x10000);
    float4* out = (float4*)d_out;

    hipMemsetAsync(gcount, 0, NBTOT * sizeof(unsigned int), stream);
    scatter_k<<<NBLK, THREADS, 0, stream>>>(ev, gcount, bins);
    render_k<<<NBTOT, RTHREADS, 0, stream>>>(gcount, bins, out);
}

// Round 21
// 83.058 us; speedup vs baseline: 1.0490x; 1.0397x over previous
//
#include <hip/hip_runtime.h>

// Event-to-image: B=16, N=500000 events (t,x,y,p) f32 -> (16,720,1280,3) f32.
// Last-event-wins per pixel: p==1 -> (0,255,255); p==0 -> (255,0,255);
// untouched -> (255,255,510). Order-independent via max over
// key = ((event_idx+1)<<1)|p (20 bits), pk = pos<<20 | key,
// pos = (y - 3*band)*1280 + x (<3840, 12 bits) -- 3-row bands (240/batch).
//
// R21 = R17 (81.7us; best fused family) with render's gather MLP-batched,
// mirroring R13's scatter fix (45->29us): per round, 4 binary searches
// (LDS-only) -> 4 independent global loads -> 4 LDS atomics. The gather is
// the proven slack (R19: winner ~28us for ~8us of traffic, latency-bound;
// bins reads cross XCD L2s at ~700cy). 4x MLP halves the serial rounds.

#define WIDTH   1280
#define HEIGHT  720
#define BATCH   16
#define NEV     500000
#define THREADS 512                         // scatter block
#define EPT     16
#define EVPB    (THREADS * EPT)             // 8192 events per block
#define BPB     ((NEV + EVPB - 1) / EVPB)   // 62 blocks per batch
#define NBLK    (BATCH * BPB)               // 992
#define NBANDS  240                         // 3-row bands per batch
#define PH      (NBANDS + 1)                // 241 prefix rows
#define RTHREADS 256                        // render block
#define BPX     (3 * WIDTH)                 // 3840 pixels per band

typedef float f4 __attribute__((ext_vector_type(4)));

// ws layout: [0, 956KB)=pref_g (band-major); [0x400000, +32.5MB)=bins

__global__ __launch_bounds__(THREADS, 8) void scatter_k(const float4* __restrict__ ev,
                                                        unsigned int* __restrict__ pref_g,
                                                        unsigned int* __restrict__ bins) {
    __shared__ unsigned int hist[NBANDS];
    __shared__ unsigned int offs[NBANDS];
    __shared__ unsigned int stage[EVPB];     // 32 KB (total ~34 KB -> 4 blocks/CU)

    int t = threadIdx.x;
    int batch = blockIdx.x / BPB;
    int blk   = blockIdx.x % BPB;
    int ev0   = blk * EVPB;
    int cnt   = NEV - ev0; if (cnt > EVPB) cnt = EVPB;
    const f4* bevv = (const f4*)(ev + (size_t)batch * NEV + ev0);

    if (t < NBANDS) hist[t] = 0u;
    __syncthreads();

    // pass 1: ONE global read (nt, batched x4 for MLP), pack to registers
    unsigned int pkd[EPT];   // bd<<22 | y<<12 | x<<1 | p ; 0xFFFFFFFF = tail
    if (cnt == EVPB) {
#pragma unroll
        for (int h = 0; h < EPT / 4; ++h) {
            f4 vv[4];
#pragma unroll
            for (int k = 0; k < 4; ++k)
                vv[k] = __builtin_nontemporal_load(&bevv[t + (h * 4 + k) * THREADS]);
#pragma unroll
            for (int k = 0; k < 4; ++k) {
                unsigned int yi = (unsigned int)(int)vv[k].z;
                unsigned int xi = (unsigned int)(int)vv[k].y;
                unsigned int pb = (vv[k].w == 1.0f) ? 1u : 0u;
                unsigned int bd = yi / 3u;
                pkd[h * 4 + k] = (bd << 22) | (yi << 12) | (xi << 1) | pb;
                atomicAdd(&hist[bd], 1u);
            }
        }
    } else {
#pragma unroll
        for (int k = 0; k < EPT; ++k) {
            int e = t + k * THREADS;
            unsigned int c = 0xFFFFFFFFu;
            if (e < cnt) {
                f4 v = __builtin_nontemporal_load(&bevv[e]);
                unsigned int yi = (unsigned int)(int)v.z;
                unsigned int xi = (unsigned int)(int)v.y;
                unsigned int pb = (v.w == 1.0f) ? 1u : 0u;
                unsigned int bd = yi / 3u;
                c = (bd << 22) | (yi << 12) | (xi << 1) | pb;
                atomicAdd(&hist[bd], 1u);
            }
            pkd[k] = c;
        }
    }
    __syncthreads();

    // exclusive prefix over 240 bands: wave 0 only, threads 0..59 own 4 bands
    if (t < 60) {
        int b4 = t * 4;
        unsigned int own = hist[b4] + hist[b4 + 1] + hist[b4 + 2] + hist[b4 + 3];
        unsigned int incl = own;
        for (int d = 1; d < 64; d <<= 1) {
            unsigned int n = __shfl_up(incl, d);
            if (t >= d) incl += n;
        }
        unsigned int run = incl - own;
        offs[b4] = run;          run += hist[b4];
        offs[b4 + 1] = run;      run += hist[b4 + 1];
        offs[b4 + 2] = run;      run += hist[b4 + 2];
        offs[b4 + 3] = run;
    }
    __syncthreads();

    // publish band-major prefix BEFORE pass 2 mutates offs:
    // pref[(r*BATCH + batch)*BPB + blk]; row NBANDS = total (=cnt)
    {
        unsigned int* pp = pref_g + (size_t)batch * BPB + blk;
        for (int r = t; r < PH; r += THREADS)
            pp[(size_t)r * (BATCH * BPB)] = (r < NBANDS) ? offs[r] : (unsigned int)cnt;
    }
    __syncthreads();

    // pass 2: from REGISTERS, rank, place band-sorted into stage
    if (cnt == EVPB) {
#pragma unroll
        for (int k = 0; k < EPT; ++k) {
            unsigned int c   = pkd[k];
            unsigned int bd  = c >> 22;
            unsigned int yi  = (c >> 12) & 0x3FFu;
            unsigned int xi  = (c >> 1) & 0x7FFu;
            unsigned int pos = (yi - bd * 3u) * 1280u + xi;
            unsigned int e   = (unsigned int)(t + k * THREADS);
            unsigned int pk  = (pos << 20)
                             | (((unsigned int)ev0 + e + 1u) << 1) | (c & 1u);
            unsigned int slot = atomicAdd(&offs[bd], 1u);
            stage[slot] = pk;
        }
    } else {
#pragma unroll
        for (int k = 0; k < EPT; ++k) {
            unsigned int c = pkd[k];
            if (c != 0xFFFFFFFFu) {
                unsigned int bd  = c >> 22;
                unsigned int yi  = (c >> 12) & 0x3FFu;
                unsigned int xi  = (c >> 1) & 0x7FFu;
                unsigned int pos = (yi - bd * 3u) * 1280u + xi;
                unsigned int e   = (unsigned int)(t + k * THREADS);
                unsigned int pk  = (pos << 20)
                                 | (((unsigned int)ev0 + e + 1u) << 1) | (c & 1u);
                unsigned int slot = atomicAdd(&offs[bd], 1u);
                stage[slot] = pk;
            }
        }
    }
    __syncthreads();

    // write the sorted chunk, fully coalesced (keep in L2/L3 for render)
    uint4* dst = (uint4*)(bins + (size_t)blockIdx.x * EVPB);
    const uint4* src = (const uint4*)stage;
    for (int k = t; k < EVPB / 4; k += THREADS)
        dst[k] = src[k];
}

__global__ __launch_bounds__(RTHREADS) void render_k(const unsigned int* __restrict__ pref_g,
                                                     const unsigned int* __restrict__ bins,
                                                     float4* __restrict__ out) {
    __shared__ unsigned int win[BPX];        // 3840 px, 15 KB
    __shared__ unsigned int segbase[BPB];
    __shared__ unsigned int segpref[65];

    int t = threadIdx.x;
    int bandid = blockIdx.x;                 // batch*240 + band
    int batch = bandid / NBANDS;
    int band  = bandid - batch * NBANDS;

    // issue the two coalesced pref rows first; zero win while they fly
    unsigned int p0 = 0u, p1 = 0u;
    if (t < BPB) {
        const unsigned int* r0 = pref_g + ((size_t)band * BATCH + batch) * BPB;
        const unsigned int* r1 = pref_g + ((size_t)(band + 1) * BATCH + batch) * BPB;
        p0 = r0[t];
        p1 = r1[t];
    }
    for (int x = t; x < BPX; x += RTHREADS) win[x] = 0u;

    unsigned int mycnt = 0u;
    if (t < BPB) {
        segbase[t] = (unsigned int)((batch * BPB + t) * EVPB) + p0;
        mycnt = p1 - p0;
    }
    if (t < 64) {                            // wave-0 inclusive scan of 62 counts
        unsigned int v = mycnt;
        for (int d = 1; d < 64; d <<= 1) {
            unsigned int n = __shfl_up(v, d);
            if (t >= d) v += n;
        }
        if (t == 0) segpref[0] = 0u;
        segpref[t + 1] = v;
    }
    __syncthreads();

    // gather, MLP-batched x4 (R13's scatter fix applied here):
    // 4 binary searches (LDS-only) -> 4 independent loads -> 4 LDS atomics
    unsigned int total = segpref[BPB];       // ~2083
    for (unsigned int j0 = t; j0 < total; j0 += 4u * RTHREADS) {
        unsigned int addr[4];
#pragma unroll
        for (int q = 0; q < 4; ++q) {
            unsigned int j = j0 + (unsigned int)q * RTHREADS;
            unsigned int a = 0xFFFFFFFFu;
            if (j < total) {
                int lo = 0, hi = BPB - 1;    // largest s with segpref[s] <= j
                while (lo < hi) {
                    int mid = (lo + hi + 1) >> 1;
                    if (segpref[mid] <= j) lo = mid; else hi = mid - 1;
                }
                a = segbase[lo] + (j - segpref[lo]);
            }
            addr[q] = a;
        }
        unsigned int pk[4];
#pragma unroll
        for (int q = 0; q < 4; ++q)
            pk[q] = (addr[q] != 0xFFFFFFFFu) ? bins[addr[q]] : 0u;
#pragma unroll
        for (int q = 0; q < 4; ++q)
            if (pk[q]) atomicMax(&win[pk[q] >> 20], pk[q] & 0xFFFFFu);
    }
    __syncthreads();

    // write three image rows: 2880 float4, one per thread per iteration
    // (lane-contiguous 1024B per store instruction), plain stores
    float4* orow = (float4*)out + (size_t)bandid * (BPX * 3 / 4);
    for (int j = t; j < BPX * 3 / 4; j += RTHREADS) {
        float vals[4];
#pragma unroll
        for (int c = 0; c < 4; ++c) {
            int fi = j * 4 + c;
            int px = fi / 3;
            int ch = fi - px * 3;
            unsigned int k = win[px];
            float val;
            if (k == 0u) val = (ch == 2) ? 510.0f : 255.0f;
            else if (ch == 2) val = 255.0f;
            else if (ch == 0) val = (k & 1u) ? 0.0f : 255.0f;
            else              val = (k & 1u) ? 255.0f : 0.0f;
            vals[c] = val;
        }
        orow[j] = make_float4(vals[0], vals[1], vals[2], vals[3]);
    }
}

extern "C" void kernel_launch(void* const* d_in, const int* in_sizes, int n_in,
                              void* d_out, int out_size, void* d_ws, size_t ws_size,
                              hipStream_t stream) {
    const float4* ev = (const float4*)d_in[0];
    unsigned int* pref_g = (unsigned int*)d_ws;
    unsigned int* bins   = (unsigned int*)((char*)d_ws + 0x400000);
    float4* out = (float4*)d_out;

    scatter_k<<<NBLK, THREADS, 0, stream>>>(ev, pref_g, bins);
    render_k<<<BATCH * NBANDS, RTHREADS, 0, stream>>>(pref_g, bins, out);
}

// Round 22
// 79.972 us; speedup vs baseline: 1.0895x; 1.0386x over previous
//
#include <hip/hip_runtime.h>

// Event-to-image: B=16, N=500000 events (t,x,y,p) f32 -> (16,720,1280,3) f32.
// Last-event-wins per pixel: p==1 -> (0,255,255); p==0 -> (255,0,255);
// untouched -> (255,255,510). Order-independent via max over
// key = ((event_idx+1)<<1)|p (20 bits), pk = pos<<20 | key,
// pos = (y&1)*1280 + x (12 bits) -- 2-row bands.
//
// R22 = R14 (80.8us best; scatter untouched) + render gather via
// global_load_lds DMA: wave w async-stages segments {w,w+4,...} densely into
// stage[segpref[s]..] (exec-masked tails), one barrier drain, then merge
// from LDS (contiguous ds_reads, no search) + proven interleaved stores.
// R9/R15/R17/R18/R19/R21 falsified search/preamble/store/split/MLP-4;
// this removes the VGPR round-trip and gives unlimited async depth.
// Exact fallback (total > 1792 = lambda+10.8sigma) = R14's gather.

#define WIDTH   1280
#define HEIGHT  720
#define BATCH   16
#define NEV     500000
#define THREADS 512                         // scatter block
#define EPT     16
#define EVPB    (THREADS * EPT)             // 8192 events per block
#define BPB     ((NEV + EVPB - 1) / EVPB)   // 62 blocks per batch
#define NBLK    (BATCH * BPB)               // 992
#define NBANDS  360                         // 2-row bands per batch
#define PH      (NBANDS + 1)                // 361 prefix entries per block
#define RTHREADS 256                        // render block
#define STCAP   1792                        // staged events cap (10.8 sigma)

typedef float f4 __attribute__((ext_vector_type(4)));
typedef const __attribute__((address_space(1))) unsigned int GU;
typedef __attribute__((address_space(3))) unsigned int LU;

// ws layout: [0, NBLK*PH*4)=pref_g (1.43 MB); [0x400000, +NBLK*EVPB*4)=bins (32.5 MB)

__global__ __launch_bounds__(THREADS, 8) void scatter_k(const float4* __restrict__ ev,
                                                        unsigned int* __restrict__ pref_g,
                                                        unsigned int* __restrict__ bins) {
    __shared__ unsigned int hist[NBANDS];
    __shared__ unsigned int offs[NBANDS];
    __shared__ unsigned int wtot[8];
    __shared__ unsigned int stage[EVPB];     // 32 KB (total ~34.9 KB -> 4 blocks/CU)

    int t = threadIdx.x;
    int batch = blockIdx.x / BPB;
    int blk   = blockIdx.x % BPB;
    int ev0   = blk * EVPB;
    int cnt   = NEV - ev0; if (cnt > EVPB) cnt = EVPB;
    const f4* bevv = (const f4*)(ev + (size_t)batch * NEV + ev0);

    if (t < NBANDS) hist[t] = 0u;
    __syncthreads();

    // pass 1: ONE global read (nt), pack to registers, histogram
    unsigned int pkd[EPT];                   // y<<12 | x<<1 | p ; 0xFFFFFFFF = tail
    if (cnt == EVPB) {
#pragma unroll
        for (int h = 0; h < EPT / 4; ++h) {
            f4 vv[4];
#pragma unroll
            for (int k = 0; k < 4; ++k)
                vv[k] = __builtin_nontemporal_load(&bevv[t + (h * 4 + k) * THREADS]);
#pragma unroll
            for (int k = 0; k < 4; ++k) {
                unsigned int yi = (unsigned int)(int)vv[k].z;
                unsigned int xi = (unsigned int)(int)vv[k].y;
                unsigned int pb = (vv[k].w == 1.0f) ? 1u : 0u;
                pkd[h * 4 + k] = (yi << 12) | (xi << 1) | pb;
                atomicAdd(&hist[yi >> 1], 1u);
            }
        }
    } else {
#pragma unroll
        for (int k = 0; k < EPT; ++k) {
            int e = t + k * THREADS;
            unsigned int c = 0xFFFFFFFFu;
            if (e < cnt) {
                f4 v = __builtin_nontemporal_load(&bevv[e]);
                unsigned int yi = (unsigned int)(int)v.z;
                unsigned int xi = (unsigned int)(int)v.y;
                unsigned int pb = (v.w == 1.0f) ? 1u : 0u;
                c = (yi << 12) | (xi << 1) | pb;
                atomicAdd(&hist[yi >> 1], 1u);
            }
            pkd[k] = c;
        }
    }
    __syncthreads();

    // exclusive prefix over 360 bands: threads 0..89 own 4 bands; shfl scan
    unsigned int own = 0u;
    int b4 = t * 4;
    if (t < 90) own = hist[b4] + hist[b4 + 1] + hist[b4 + 2] + hist[b4 + 3];
    unsigned int incl = own;
    for (int d = 1; d < 64; d <<= 1) {
        unsigned int n = __shfl_up(incl, d);
        if ((t & 63) >= d) incl += n;
    }
    if ((t & 63) == 63) wtot[t >> 6] = incl;   // waves 2..7 contribute 0
    __syncthreads();
    unsigned int wbase = 0u;
    for (int w = 0; w < (t >> 6); ++w) wbase += wtot[w];
    unsigned int total = 0u;
    for (int w = 0; w < 8; ++w) total += wtot[w];        // == cnt
    if (t < 90) {
        unsigned int run = wbase + incl - own;
        offs[b4] = run;          run += hist[b4];
        offs[b4 + 1] = run;      run += hist[b4 + 1];
        offs[b4 + 2] = run;      run += hist[b4 + 2];
        offs[b4 + 3] = run;
    }
    __syncthreads();

    // publish per-block band prefix BEFORE pass 2 mutates offs
    unsigned int* pg = pref_g + (size_t)blockIdx.x * PH;
    if (t < PH) pg[t] = (t < NBANDS) ? offs[t] : total;
    __syncthreads();

    // pass 2: from REGISTERS, rank, place sorted in stage
    if (cnt == EVPB) {
#pragma unroll
        for (int k = 0; k < EPT; ++k) {
            unsigned int c   = pkd[k];
            unsigned int yi  = c >> 12;
            unsigned int xi  = (c >> 1) & 0x7FFu;
            unsigned int pos = (yi & 1u) * 1280u + xi;
            unsigned int e   = (unsigned int)(t + k * THREADS);
            unsigned int pk  = (pos << 20)
                             | (((unsigned int)ev0 + e + 1u) << 1) | (c & 1u);
            unsigned int slot = atomicAdd(&offs[yi >> 1], 1u);
            stage[slot] = pk;
        }
    } else {
#pragma unroll
        for (int k = 0; k < EPT; ++k) {
            unsigned int c = pkd[k];
            if (c != 0xFFFFFFFFu) {
                unsigned int yi  = c >> 12;
                unsigned int xi  = (c >> 1) & 0x7FFu;
                unsigned int pos = (yi & 1u) * 1280u + xi;
                unsigned int e   = (unsigned int)(t + k * THREADS);
                unsigned int pk  = (pos << 20)
                                 | (((unsigned int)ev0 + e + 1u) << 1) | (c & 1u);
                unsigned int slot = atomicAdd(&offs[yi >> 1], 1u);
                stage[slot] = pk;
            }
        }
    }
    __syncthreads();

    // write the sorted chunk, fully coalesced (keep in L2/L3 for render)
    uint4* dst = (uint4*)(bins + (size_t)blockIdx.x * EVPB);
    const uint4* src = (const uint4*)stage;
    for (int k = t; k < EVPB / 4; k += THREADS)
        dst[k] = src[k];
}

__global__ __launch_bounds__(RTHREADS) void render_k(const unsigned int* __restrict__ pref_g,
                                                     const unsigned int* __restrict__ bins,
                                                     float4* __restrict__ out) {
    __shared__ unsigned int win[2 * WIDTH];  // 10 KB
    __shared__ unsigned int stage[STCAP];    // 7 KB dense staged events
    __shared__ unsigned int segbase[BPB];
    __shared__ unsigned int segpref[65];

    int t = threadIdx.x;
    int bandid = blockIdx.x;                 // batch*360 + band
    int batch = bandid / NBANDS;
    int band  = bandid - batch * NBANDS;

    // issue scattered pref loads first; zero win while they fly
    unsigned int p0 = 0u, p1 = 0u;
    if (t < BPB) {
        const unsigned int* pg = pref_g + (size_t)(batch * BPB + t) * PH + band;
        p0 = pg[0]; p1 = pg[1];
    }
    for (int x = t; x < 2 * WIDTH; x += RTHREADS) win[x] = 0u;

    unsigned int mycnt = 0u;
    if (t < BPB) {
        segbase[t] = (unsigned int)((batch * BPB + t) * EVPB) + p0;
        mycnt = p1 - p0;
    }
    if (t < 64) {                            // wave-0 inclusive scan of 62 counts
        unsigned int v = mycnt;
        for (int d = 1; d < 64; d <<= 1) {
            unsigned int n = __shfl_up(v, d);
            if (t >= d) v += n;
        }
        if (t == 0) segpref[0] = 0u;
        segpref[t + 1] = v;
    }
    __syncthreads();

    unsigned int total = segpref[BPB];       // ~1389
    if (total <= STCAP) {
        // async DMA: wave w stages segments {w, w+4, ...} densely into stage
        int w = t >> 6, lane = t & 63;
        for (int s = w; s < BPB; s += RTHREADS / 64) {
            unsigned int sp = segpref[s];
            unsigned int cn = segpref[s + 1] - sp;
            unsigned int gb = segbase[s];
            for (unsigned int off = 0; off < cn; off += 64u) {
                if ((unsigned int)lane < cn - off) {
                    GU* gsrc = (GU*)(bins + gb + off + (unsigned int)lane);
                    __builtin_amdgcn_global_load_lds(gsrc, (LU*)&stage[sp + off], 4, 0, 0);
                }
            }
        }
        __syncthreads();                     // compiler drains vmcnt before barrier

        // merge from dense LDS: contiguous ds_reads, no search
        for (unsigned int j = t; j < total; j += RTHREADS) {
            unsigned int pk = stage[j];
            atomicMax(&win[pk >> 20], pk & 0xFFFFFu);
        }
    } else {
        // exact fallback (P ~ 1e-26, block-uniform): R14's search gather
        for (unsigned int j = t; j < total; j += RTHREADS) {
            int lo = 0, hi = BPB - 1;
            while (lo < hi) {
                int mid = (lo + hi + 1) >> 1;
                if (segpref[mid] <= j) lo = mid; else hi = mid - 1;
            }
            unsigned int pk = bins[segbase[lo] + (j - segpref[lo])];
            atomicMax(&win[pk >> 20], pk & 0xFFFFFu);
        }
    }
    __syncthreads();

    // write two image rows: 1920 float4, one per thread per iteration
    // (lane-contiguous 1024B per store instruction)
    f4* orow = (f4*)out + (size_t)bandid * (2 * WIDTH * 3 / 4);
    for (int j = t; j < 2 * WIDTH * 3 / 4; j += RTHREADS) {
        float vals[4];
#pragma unroll
        for (int c = 0; c < 4; ++c) {
            int fi = j * 4 + c;
            int px = fi / 3;
            int ch = fi - px * 3;
            unsigned int k = win[px];
            float val;
            if (k == 0u) val = (ch == 2) ? 510.0f : 255.0f;
            else if (ch == 2) val = 255.0f;
            else if (ch == 0) val = (k & 1u) ? 0.0f : 255.0f;
            else              val = (k & 1u) ? 255.0f : 0.0f;
            vals[c] = val;
        }
        f4 o = { vals[0], vals[1], vals[2], vals[3] };
        __builtin_nontemporal_store(o, orow + j);
    }
}

extern "C" void kernel_launch(void* const* d_in, const int* in_sizes, int n_in,
                              void* d_out, int out_size, void* d_ws, size_t ws_size,
                              hipStream_t stream) {
    const float4* ev = (const float4*)d_in[0];
    unsigned int* pref_g = (unsigned int*)d_ws;
    unsigned int* bins   = (unsigned int*)((char*)d_ws + 0x400000);
    float4* out = (float4*)d_out;

    scatter_k<<<NBLK, THREADS, 0, stream>>>(ev, pref_g, bins);
    render_k<<<BATCH * NBANDS, RTHREADS, 0, stream>>>(pref_g, bins, out);
}